// Round 3
// baseline (46.976 us; speedup 1.0000x reference)
//
#include <hip/hip_runtime.h>

#define D  128   // EMB
#define KN 128   // K_N
#define NB 16    // batch rows per prep block
#define LOG2E 1.44269504088896340736f

__device__ __forceinline__ float negexp(float v) {              // e^{-v}
    return __builtin_amdgcn_exp2f(v * -LOG2E);
}
__device__ __forceinline__ float sigf(float x) {                // sigmoid
    return __builtin_amdgcn_rcpf(1.0f + negexp(x));
}

// ---------------------------------------------------------------------------
// Kernel A: per-(e,k) tables with bias folded and exp applied.
//   E1t[e*128+k] = exp(-(sum_d kn[k,d]*|W1[e,128+d]| + b1[e]))
//   E2t[e*128+k] = exp(-(sum_d kn[k,d]*|W2[e,128+d]| + b2[e]))
// grid = 128 blocks (e), block = 128 threads (k)
// ---------------------------------------------------------------------------
__global__ __launch_bounds__(128) void tables_kernel(
    const float* __restrict__ kn, const float* __restrict__ W1, const float* __restrict__ b1,
    const float* __restrict__ W2, const float* __restrict__ b2,
    float* __restrict__ E1t, float* __restrict__ E2t)
{
    const int e = blockIdx.x, k = threadIdx.x;
    const float4* knr = (const float4*)(kn + k * D);
    const float4* w1r = (const float4*)(W1 + e * (2 * D) + D);
    const float4* w2r = (const float4*)(W2 + e * (2 * D) + D);
    float a1 = 0.f, a2 = 0.f;
    #pragma unroll 8
    for (int q = 0; q < D / 4; ++q) {
        float4 kv = knr[q], u = w1r[q], v = w2r[q];
        a1 = fmaf(kv.x, fabsf(u.x), a1); a1 = fmaf(kv.y, fabsf(u.y), a1);
        a1 = fmaf(kv.z, fabsf(u.z), a1); a1 = fmaf(kv.w, fabsf(u.w), a1);
        a2 = fmaf(kv.x, fabsf(v.x), a2); a2 = fmaf(kv.y, fabsf(v.y), a2);
        a2 = fmaf(kv.z, fabsf(v.z), a2); a2 = fmaf(kv.w, fabsf(v.w), a2);
    }
    E1t[e * KN + k] = negexp(a1 + b1[e]);
    E2t[e * KN + k] = negexp(a2 + b2[e]);
}

// ---------------------------------------------------------------------------
// Kernel B: per-(b,e) pack P[b*128+e] = {e^{-S1}, e^{-E2}, disc*|W3|, kq}
//   S1[b,e] = sum_d stu_v[sid,d]*|W1[e,d]|, E2 likewise with exer_v/W2
//   disc    = sigmoid(stu_q[sid,e]*exer_k[eid,e])
// block = 256 thr, NB=16 b per block. |W|^T staged in LDS (pad 132 -> no
// read conflicts, float4 16B-aligned). Thread = (4-e-group, b-pair).
// ---------------------------------------------------------------------------
__device__ __forceinline__ void emit_row(
    float4* __restrict__ P, int b, int eg,
    const float4& as, const float4& ae,
    const float* __restrict__ stu_q, const float* __restrict__ exer_k,
    const float* __restrict__ kq, const float* __restrict__ W3,
    int sid, int eid)
{
    float4 sq = *(const float4*)(stu_q + sid * D + eg * 4);
    float4 ek = *(const float4*)(exer_k + eid * D + eg * 4);
    float4 kv = *(const float4*)(kq + b * D + eg * 4);
    float4 w3 = *(const float4*)(W3 + eg * 4);
    float4* Pb = P + b * D + eg * 4;
    Pb[0] = make_float4(negexp(as.x), negexp(ae.x), sigf(sq.x * ek.x) * fabsf(w3.x), kv.x);
    Pb[1] = make_float4(negexp(as.y), negexp(ae.y), sigf(sq.y * ek.y) * fabsf(w3.y), kv.y);
    Pb[2] = make_float4(negexp(as.z), negexp(ae.z), sigf(sq.z * ek.z) * fabsf(w3.z), kv.z);
    Pb[3] = make_float4(negexp(as.w), negexp(ae.w), sigf(sq.w * ek.w) * fabsf(w3.w), kv.w);
}

__global__ __launch_bounds__(256) void prep_kernel(
    const int* __restrict__ stu_id, const int* __restrict__ exer_id,
    const float* __restrict__ kq,
    const float* __restrict__ stu_q, const float* __restrict__ exer_k,
    const float* __restrict__ stu_v, const float* __restrict__ exer_v,
    const float* __restrict__ W1, const float* __restrict__ W2,
    const float* __restrict__ W3,
    float4* __restrict__ P, int B)
{
    __shared__ float W1T[D][132];        // |W1a|^T : W1T[d][e]
    __shared__ float W2T[D][132];
    __shared__ float SV[NB][D];
    __shared__ float EV[NB][D];
    __shared__ int sids[NB], eids[NB];

    const int tid = threadIdx.x;
    const int b0  = blockIdx.x * NB;

    if (tid < NB) {
        int b = b0 + tid;
        sids[tid] = stu_id[b < B ? b : 0];
        eids[tid] = exer_id[b < B ? b : 0];
    }
    for (int i = tid; i < D * D; i += 256) {     // coalesced read, 8-way LDS write (staging only)
        int e = i >> 7, d = i & (D - 1);
        W1T[d][e] = fabsf(W1[e * (2 * D) + d]);
        W2T[d][e] = fabsf(W2[e * (2 * D) + d]);
    }
    __syncthreads();
    for (int i = tid; i < NB * D; i += 256) {
        int bi = i >> 7, d = i & (D - 1);
        SV[bi][d] = stu_v[sids[bi] * D + d];
        EV[bi][d] = exer_v[eids[bi] * D + d];
    }
    __syncthreads();

    const int eg  = tid & 31;       // 4-e group: e = eg*4+j
    const int bh  = tid >> 5;       // 0..7
    const int bi0 = 2 * bh, bi1 = 2 * bh + 1;

    float4 as0 = {0, 0, 0, 0}, as1 = as0, ae0 = as0, ae1 = as0;
    #pragma unroll 4
    for (int d = 0; d < D; ++d) {
        float4 w1 = *(const float4*)&W1T[d][eg * 4];   // conflict-minimal (pad 132)
        float4 w2 = *(const float4*)&W2T[d][eg * 4];
        float sv0 = SV[bi0][d], sv1 = SV[bi1][d];      // 2-addr broadcast (free)
        float ev0 = EV[bi0][d], ev1 = EV[bi1][d];
        as0.x = fmaf(sv0, w1.x, as0.x); as0.y = fmaf(sv0, w1.y, as0.y);
        as0.z = fmaf(sv0, w1.z, as0.z); as0.w = fmaf(sv0, w1.w, as0.w);
        as1.x = fmaf(sv1, w1.x, as1.x); as1.y = fmaf(sv1, w1.y, as1.y);
        as1.z = fmaf(sv1, w1.z, as1.z); as1.w = fmaf(sv1, w1.w, as1.w);
        ae0.x = fmaf(ev0, w2.x, ae0.x); ae0.y = fmaf(ev0, w2.y, ae0.y);
        ae0.z = fmaf(ev0, w2.z, ae0.z); ae0.w = fmaf(ev0, w2.w, ae0.w);
        ae1.x = fmaf(ev1, w2.x, ae1.x); ae1.y = fmaf(ev1, w2.y, ae1.y);
        ae1.z = fmaf(ev1, w2.z, ae1.z); ae1.w = fmaf(ev1, w2.w, ae1.w);
    }
    if (b0 + bi0 < B) emit_row(P, b0 + bi0, eg, as0, ae0, stu_q, exer_k, kq, W3, sids[bi0], eids[bi0]);
    if (b0 + bi1 < B) emit_row(P, b0 + bi1, eg, as1, ae1, stu_q, exer_k, kq, W3, sids[bi1], eids[bi1]);
}

// ---------------------------------------------------------------------------
// Kernel C: fused core.  Per (b,k):
//   pref - diff = (y - x) / ((1+x)(1+y)),  x = Ea1*E1k, y = Ea2*E2k
//   o = sigmoid(sum_e (pref-diff)*w3d + b3);  out[b] = sum_k o*kq / sum_k kq
// 512 thr (8 waves), 1 block/CU. TAB (128KB LDS) = interleaved {E1,E1,E2,E2}
// per k-pair -> one ds_read_b128/iter; P row broadcast from 2KB/wave LDS.
// Wave owns one b; lane owns k=2l,2l+1; shuffle-reduce over k at the end.
// ---------------------------------------------------------------------------
__global__ __launch_bounds__(512) void main_kernel(
    const float4* __restrict__ P,
    const float2* __restrict__ E1t2, const float2* __restrict__ E2t2,
    const float* __restrict__ b3p, float* __restrict__ out, int B)
{
    __shared__ float4 TAB[D * 64];   // [e][l] = {E1(e,2l),E1(e,2l+1),E2(e,2l),E2(e,2l+1)}
    __shared__ float4 PW[8][D];      // per-wave P row {Ea1,Ea2,w3d,kq}

    const int tid = threadIdx.x;
    for (int j = tid; j < D * 64; j += 512) {
        float2 u1 = E1t2[j], u2 = E2t2[j];
        TAB[j] = make_float4(u1.x, u1.y, u2.x, u2.y);
    }
    __syncthreads();

    const int wid = tid >> 6, lane = tid & 63;
    const float b3v = b3p[0];

    for (int ib = wid; ib < 16; ib += 8) {
        const int b = blockIdx.x * 16 + ib;
        if (b >= B) break;
        PW[wid][lane]      = P[b * D + lane];
        PW[wid][lane + 64] = P[b * D + lane + 64];
        float acc0 = 0.f, acc1 = 0.f;
        #pragma unroll 4
        for (int e = 0; e < D; ++e) {
            float4 p = PW[wid][e];          // broadcast
            float4 t = TAB[e * 64 + lane];  // conflict-minimal b128
            float x0 = p.x * t.x, x1 = p.x * t.y;
            float y0 = p.y * t.z, y1 = p.y * t.w;
            float n0 = (y0 - x0) * p.z;
            float n1 = (y1 - x1) * p.z;
            float d0 = fmaf(x0, y0, x0 + y0 + 1.0f);   // (1+x)(1+y)
            float d1 = fmaf(x1, y1, x1 + y1 + 1.0f);
            acc0 = fmaf(n0, __builtin_amdgcn_rcpf(d0), acc0);
            acc1 = fmaf(n1, __builtin_amdgcn_rcpf(d1), acc1);
        }
        float o0 = sigf(acc0 + b3v);
        float o1 = sigf(acc1 + b3v);
        float kq0 = PW[wid][2 * lane].w;
        float kq1 = PW[wid][2 * lane + 1].w;
        float num = fmaf(o0, kq0, o1 * kq1);
        float den = kq0 + kq1;
        #pragma unroll
        for (int off = 32; off > 0; off >>= 1) {
            num += __shfl_xor(num, off);
            den += __shfl_xor(den, off);
        }
        if (lane == 0) out[b] = num / den;
    }
}

// ---------------------------------------------------------------------------
extern "C" void kernel_launch(void* const* d_in, const int* in_sizes, int n_in,
                              void* d_out, int out_size, void* d_ws, size_t ws_size,
                              hipStream_t stream)
{
    const int*   stu_id      = (const int*)  d_in[0];
    const int*   exer_id     = (const int*)  d_in[1];
    const float* kq          = (const float*)d_in[2];
    const float* student_q   = (const float*)d_in[3];
    const float* exercise_k  = (const float*)d_in[4];
    const float* student_v   = (const float*)d_in[5];
    const float* exercise_v  = (const float*)d_in[6];
    const float* knowledge_v = (const float*)d_in[7];
    const float* W1 = (const float*)d_in[8];
    const float* b1 = (const float*)d_in[9];
    const float* W2 = (const float*)d_in[10];
    const float* b2 = (const float*)d_in[11];
    const float* W3 = (const float*)d_in[12];
    const float* b3 = (const float*)d_in[13];
    float* out = (float*)d_out;
    const int B = in_sizes[0];

    // workspace layout: E1t (64KB) | E2t (64KB) | P (B*128*16 = 8MB @ B=4096)
    float*  E1t = (float*)d_ws;
    float*  E2t = E1t + D * KN;
    float4* P   = (float4*)((char*)d_ws + (size_t)(2 * D * KN) * sizeof(float));

    tables_kernel<<<D, KN, 0, stream>>>(knowledge_v, W1, b1, W2, b2, E1t, E2t);
    prep_kernel<<<(B + NB - 1) / NB, 256, 0, stream>>>(
        stu_id, exer_id, kq, student_q, exercise_k, student_v, exercise_v,
        W1, W2, W3, P, B);
    main_kernel<<<(B + 15) / 16, 512, 0, stream>>>(
        P, (const float2*)E1t, (const float2*)E2t, b3, out, B);
}

// Round 4
// 37.173 us; speedup vs baseline: 1.2637x; 1.2637x over previous
//
#include <hip/hip_runtime.h>

#define D  128   // EMB
#define KN 128   // K_N
#define NB 16    // batch rows per prep block
#define LOG2E 1.44269504088896340736f

__device__ __forceinline__ float negexp(float v) {              // e^{-v}
    return __builtin_amdgcn_exp2f(v * -LOG2E);
}
__device__ __forceinline__ float sigf(float x) {                // sigmoid
    return __builtin_amdgcn_rcpf(1.0f + negexp(x));
}

// ---------------------------------------------------------------------------
// Kernel 1: fused prep + tables.
// 256 blocks x 512 threads.
//   threads 0..255  : prep role -- per-(b,e) pack
//       P[b*128+e] = {e^{-S1}, e^{-E2}, disc*|W3|, kq}
//       via |W|^T staged in LDS (pad 132 -> 4-cyc-optimal float4 reads)
//   threads 256..511, blocks 0..63 : tables role (rides in prep's VALU shadow)
//       TABG[e*64+l] = {e^{-(K1+b1)}(e,2l), (e,2l+1), e^{-(K2+b2)}(e,2l), (e,2l+1)}
//       K1(e,k) = sum_d kn[k,d]*|W1[e,128+d]|   (64 blocks x 256 thr = 16384 entries)
// ---------------------------------------------------------------------------
__device__ __forceinline__ void emit_row(
    float4* __restrict__ P, int b, int eg,
    const float4& as, const float4& ae,
    const float* __restrict__ stu_q, const float* __restrict__ exer_k,
    const float* __restrict__ kq, const float* __restrict__ W3,
    int sid, int eid)
{
    float4 sq = *(const float4*)(stu_q + sid * D + eg * 4);
    float4 ek = *(const float4*)(exer_k + eid * D + eg * 4);
    float4 kv = *(const float4*)(kq + b * D + eg * 4);
    float4 w3 = *(const float4*)(W3 + eg * 4);
    float4* Pb = P + b * D + eg * 4;
    Pb[0] = make_float4(negexp(as.x), negexp(ae.x), sigf(sq.x * ek.x) * fabsf(w3.x), kv.x);
    Pb[1] = make_float4(negexp(as.y), negexp(ae.y), sigf(sq.y * ek.y) * fabsf(w3.y), kv.y);
    Pb[2] = make_float4(negexp(as.z), negexp(ae.z), sigf(sq.z * ek.z) * fabsf(w3.z), kv.z);
    Pb[3] = make_float4(negexp(as.w), negexp(ae.w), sigf(sq.w * ek.w) * fabsf(w3.w), kv.w);
}

__global__ __launch_bounds__(512) void k1_kernel(
    const int* __restrict__ stu_id, const int* __restrict__ exer_id,
    const float* __restrict__ kq,
    const float* __restrict__ stu_q, const float* __restrict__ exer_k,
    const float* __restrict__ stu_v, const float* __restrict__ exer_v,
    const float* __restrict__ kn,
    const float* __restrict__ W1, const float* __restrict__ b1,
    const float* __restrict__ W2, const float* __restrict__ b2,
    const float* __restrict__ W3,
    float4* __restrict__ P, float* __restrict__ TABGf, int B)
{
    __shared__ float W1T[D][132];        // |W1[:, :128]|^T : W1T[d][e]
    __shared__ float W2T[D][132];
    __shared__ float SV[NB][D];
    __shared__ float EV[NB][D];
    __shared__ int sids[NB], eids[NB];

    const int tid = threadIdx.x;
    const int b0  = blockIdx.x * NB;

    if (tid < NB) {
        int b = b0 + tid;
        sids[tid] = stu_id[b < B ? b : 0];
        eids[tid] = exer_id[b < B ? b : 0];
    }
    for (int i = tid; i < D * D; i += 512) {     // coalesced global read
        int e = i >> 7, d = i & (D - 1);
        W1T[d][e] = fabsf(W1[e * (2 * D) + d]);
        W2T[d][e] = fabsf(W2[e * (2 * D) + d]);
    }
    __syncthreads();
    for (int i = tid; i < NB * D; i += 512) {
        int bi = i >> 7, d = i & (D - 1);
        SV[bi][d] = stu_v[sids[bi] * D + d];
        EV[bi][d] = exer_v[eids[bi] * D + d];
    }
    __syncthreads();

    if (tid < 256) {
        // ---- prep role: thread = (eg 0..31 -> 4 e's, bh 0..7 -> 2 b's) ----
        const int eg  = tid & 31;
        const int bh  = tid >> 5;
        const int bi0 = 2 * bh, bi1 = 2 * bh + 1;

        float4 as0 = {0, 0, 0, 0}, as1 = as0, ae0 = as0, ae1 = as0;
        #pragma unroll 4
        for (int d = 0; d < D; ++d) {
            float4 w1 = *(const float4*)&W1T[d][eg * 4];   // 512B distinct -> 4-cyc optimal
            float4 w2 = *(const float4*)&W2T[d][eg * 4];
            float sv0 = SV[bi0][d], sv1 = SV[bi1][d];      // 2-addr broadcast
            float ev0 = EV[bi0][d], ev1 = EV[bi1][d];
            as0.x = fmaf(sv0, w1.x, as0.x); as0.y = fmaf(sv0, w1.y, as0.y);
            as0.z = fmaf(sv0, w1.z, as0.z); as0.w = fmaf(sv0, w1.w, as0.w);
            as1.x = fmaf(sv1, w1.x, as1.x); as1.y = fmaf(sv1, w1.y, as1.y);
            as1.z = fmaf(sv1, w1.z, as1.z); as1.w = fmaf(sv1, w1.w, as1.w);
            ae0.x = fmaf(ev0, w2.x, ae0.x); ae0.y = fmaf(ev0, w2.y, ae0.y);
            ae0.z = fmaf(ev0, w2.z, ae0.z); ae0.w = fmaf(ev0, w2.w, ae0.w);
            ae1.x = fmaf(ev1, w2.x, ae1.x); ae1.y = fmaf(ev1, w2.y, ae1.y);
            ae1.z = fmaf(ev1, w2.z, ae1.z); ae1.w = fmaf(ev1, w2.w, ae1.w);
        }
        if (b0 + bi0 < B) emit_row(P, b0 + bi0, eg, as0, ae0, stu_q, exer_k, kq, W3, sids[bi0], eids[bi0]);
        if (b0 + bi1 < B) emit_row(P, b0 + bi1, eg, as1, ae1, stu_q, exer_k, kq, W3, sids[bi1], eids[bi1]);
    } else if (blockIdx.x < 64) {
        // ---- tables role: entry idx over 128e x 128k ----
        const int idx = blockIdx.x * 256 + (tid - 256);
        const int e = idx >> 7, k = idx & (KN - 1);
        const float4* knr = (const float4*)(kn + k * D);
        const float4* w1r = (const float4*)(W1 + e * (2 * D) + D);
        const float4* w2r = (const float4*)(W2 + e * (2 * D) + D);
        float a1 = 0.f, a2 = 0.f;
        #pragma unroll 8
        for (int q = 0; q < D / 4; ++q) {
            float4 kv = knr[q], u = w1r[q], v = w2r[q];
            a1 = fmaf(kv.x, fabsf(u.x), a1); a1 = fmaf(kv.y, fabsf(u.y), a1);
            a1 = fmaf(kv.z, fabsf(u.z), a1); a1 = fmaf(kv.w, fabsf(u.w), a1);
            a2 = fmaf(kv.x, fabsf(v.x), a2); a2 = fmaf(kv.y, fabsf(v.y), a2);
            a2 = fmaf(kv.z, fabsf(v.z), a2); a2 = fmaf(kv.w, fabsf(v.w), a2);
        }
        // interleaved TAB layout: float4[e*64+l] = {E1(2l),E1(2l+1),E2(2l),E2(2l+1)}
        const int base = e * 256 + (k >> 1) * 4 + (k & 1);
        TABGf[base]     = negexp(a1 + b1[e]);
        TABGf[base + 2] = negexp(a2 + b2[e]);
    }
}

// ---------------------------------------------------------------------------
// Kernel 2: fused core.  Per (b,k):
//   x' = 1+e^{-(S1+K1+b1)}, y' = 1+e^{-(E2+K2+b2)}
//   pref - diff = (y'-x')/(x'*y')      [= sigma(a)-sigma(b)]
//   o = sigmoid(sum_e (pref-diff)*pz + b3);  out[b] = sum_k o*kq / sum_k kq
// 512 thr (8 waves), 1 block/CU, 136KB LDS. Wave owns one b; lane owns
// k=2l,2l+1 (6 VALU + 1 rcp per element); shuffle-reduce over k.
// ---------------------------------------------------------------------------
__global__ __launch_bounds__(512) void main_kernel(
    const float4* __restrict__ P, const float4* __restrict__ TABG,
    const float* __restrict__ b3p, float* __restrict__ out, int B)
{
    __shared__ float4 TAB[D * 64];
    __shared__ float4 PW[8][D];      // per-wave P row {Ea1,Ea2,pz,kq}

    const int tid = threadIdx.x;
    #pragma unroll
    for (int it = 0; it < 16; ++it) {        // coalesced float4 copy, L2-hot
        int j = tid + it * 512;
        TAB[j] = TABG[j];
    }
    __syncthreads();

    const int wid = tid >> 6, lane = tid & 63;
    const float b3v = b3p[0];

    for (int ib = wid; ib < 16; ib += 8) {
        const int b = blockIdx.x * 16 + ib;
        if (b >= B) break;
        PW[wid][lane]      = P[b * D + lane];
        PW[wid][lane + 64] = P[b * D + lane + 64];
        float acc0 = 0.f, acc1 = 0.f;
        #pragma unroll 4
        for (int e = 0; e < D; ++e) {
            float4 p = PW[wid][e];          // broadcast
            float4 t = TAB[e * 64 + lane];  // 2-way aliased b128 (free)
            float x0 = fmaf(p.x, t.x, 1.0f);
            float x1 = fmaf(p.x, t.y, 1.0f);
            float y0 = fmaf(p.y, t.z, 1.0f);
            float y1 = fmaf(p.y, t.w, 1.0f);
            float n0 = (y0 - x0) * p.z;
            float n1 = (y1 - x1) * p.z;
            acc0 = fmaf(n0, __builtin_amdgcn_rcpf(x0 * y0), acc0);
            acc1 = fmaf(n1, __builtin_amdgcn_rcpf(x1 * y1), acc1);
        }
        float o0 = sigf(acc0 + b3v);
        float o1 = sigf(acc1 + b3v);
        float kq0 = PW[wid][2 * lane].w;
        float kq1 = PW[wid][2 * lane + 1].w;
        float num = fmaf(o0, kq0, o1 * kq1);
        float den = kq0 + kq1;
        #pragma unroll
        for (int off = 32; off > 0; off >>= 1) {
            num += __shfl_xor(num, off);
            den += __shfl_xor(den, off);
        }
        if (lane == 0) out[b] = num / den;
    }
}

// ---------------------------------------------------------------------------
extern "C" void kernel_launch(void* const* d_in, const int* in_sizes, int n_in,
                              void* d_out, int out_size, void* d_ws, size_t ws_size,
                              hipStream_t stream)
{
    const int*   stu_id      = (const int*)  d_in[0];
    const int*   exer_id     = (const int*)  d_in[1];
    const float* kq          = (const float*)d_in[2];
    const float* student_q   = (const float*)d_in[3];
    const float* exercise_k  = (const float*)d_in[4];
    const float* student_v   = (const float*)d_in[5];
    const float* exercise_v  = (const float*)d_in[6];
    const float* knowledge_v = (const float*)d_in[7];
    const float* W1 = (const float*)d_in[8];
    const float* b1 = (const float*)d_in[9];
    const float* W2 = (const float*)d_in[10];
    const float* b2 = (const float*)d_in[11];
    const float* W3 = (const float*)d_in[12];
    const float* b3 = (const float*)d_in[13];
    float* out = (float*)d_out;
    const int B = in_sizes[0];

    // workspace: TABG (128KB interleaved tables) | P (B*128*16 = 8MB @ B=4096)
    float*  TABGf = (float*)d_ws;
    float4* P     = (float4*)((char*)d_ws + (size_t)(D * KN * 2) * sizeof(float));

    int nprep = (B + NB - 1) / NB;
    int grid1 = nprep > 64 ? nprep : 64;    // tables role needs blocks 0..63
    k1_kernel<<<grid1, 512, 0, stream>>>(
        stu_id, exer_id, kq, student_q, exercise_k, student_v, exercise_v,
        knowledge_v, W1, b1, W2, b2, W3, P, TABGf, B);
    main_kernel<<<(B + 15) / 16, 512, 0, stream>>>(
        P, (const float4*)TABGf, b3, out, B);
}